// Round 3
// baseline (5374.097 us; speedup 1.0000x reference)
//
#include <hip/hip_runtime.h>
#include <hip/hip_bf16.h>

#define HH 64      // hidden
#define TT 256     // seq len
#define NB 1024    // batch
#define GG 256     // 4*H gates
#define DD0 5      // layer-0 input dim
#define DD1 128    // layer-1 input dim (2*H)

__device__ __forceinline__ float sigf(float x) { return 1.0f / (1.0f + __expf(-x)); }
__device__ __forceinline__ float tanh_fast(float x) { return 2.0f / (1.0f + __expf(-2.0f * x)) - 1.0f; }

// Pin an array of floats into VGPRs: volatile asm can't be sunk/rematerialized,
// so the compiler must keep the values resident across the recurrence loop.
#define PIN_F(arr, n)                                             \
    _Pragma("unroll")                                             \
    for (int _p = 0; _p < (n); ++_p) asm volatile("" : "+v"((arr)[_p]));

// ---------------------------------------------------------------------------
// Layer 0: one (row, dir) per block, 256 threads, thread j = gate j.
// 69 weight floats pinned in registers (~95 VGPR) -> 4 blocks/CU.
// ---------------------------------------------------------------------------
template <bool BF16OUT>
__launch_bounds__(256, 4)
__global__ void lstm_l0(const float* __restrict__ x,
                        const float* __restrict__ w_ih_f, const float* __restrict__ w_hh_f,
                        const float* __restrict__ b_ih_f, const float* __restrict__ b_hh_f,
                        const float* __restrict__ w_ih_r, const float* __restrict__ w_hh_r,
                        const float* __restrict__ b_ih_r, const float* __restrict__ b_hh_r,
                        void* __restrict__ out0) {
    const int tid = threadIdx.x;
    const int row = blockIdx.x >> 1;
    const int dir = blockIdx.x & 1;

    const float* w_ih = dir ? w_ih_r : w_ih_f;
    const float* w_hh = dir ? w_hh_r : w_hh_f;
    const float* b_ih = dir ? b_ih_r : b_ih_f;
    const float* b_hh = dir ? b_hh_r : b_hh_f;

    __shared__ __align__(16) float xs[TT * DD0];  // 5 KB: this row's x, all t
    __shared__ __align__(16) float hs[HH];
    __shared__ __align__(16) float gs[GG];
    __shared__ __align__(16) float bs[GG];

    {   // stage x: 1280 floats = 320 float4
        const float4* xsrc = (const float4*)(x + (size_t)row * TT * DD0);
        for (int i = tid; i < TT * DD0 / 4; i += 256) ((float4*)xs)[i] = xsrc[i];
    }
    if (tid < HH) hs[tid] = 0.0f;
    bs[tid] = b_ih[tid] + b_hh[tid];

    float wih[DD0];
#pragma unroll
    for (int d = 0; d < DD0; ++d) wih[d] = w_ih[tid * DD0 + d];
    float whh[HH];
#pragma unroll
    for (int k = 0; k < 16; ++k) ((float4*)whh)[k] = ((const float4*)(w_hh + tid * HH))[k];
    PIN_F(wih, DD0);
    PIN_F(whh, HH);

    float c = 0.0f;
    __syncthreads();

    for (int t = 0; t < TT; ++t) {
        const int tt = dir ? (TT - 1 - t) : t;
        // gate phase: all LDS reads are wave-uniform broadcasts
        float a0 = 0.f, a1 = 0.f, a2 = 0.f, a3 = 0.f;
#pragma unroll
        for (int d = 0; d < DD0; ++d) a0 += wih[d] * xs[tt * DD0 + d];
        const float4* h4 = (const float4*)hs;
#pragma unroll
        for (int kk = 0; kk < 16; ++kk) {
            float4 hv = h4[kk];
            a0 += whh[4 * kk + 0] * hv.x;
            a1 += whh[4 * kk + 1] * hv.y;
            a2 += whh[4 * kk + 2] * hv.z;
            a3 += whh[4 * kk + 3] * hv.w;
        }
        gs[tid] = (a0 + a1) + (a2 + a3);
        __syncthreads();
        if (tid < HH) {
            const int u = tid;
            float gi = gs[u] + bs[u];
            float gf = gs[u + 64] + bs[u + 64];
            float gc = gs[u + 128] + bs[u + 128];
            float go = gs[u + 192] + bs[u + 192];
            c = sigf(gf) * c + sigf(gi) * tanh_fast(gc);
            float h = sigf(go) * tanh_fast(c);
            hs[u] = h;
            size_t oidx = (size_t)row * TT * DD1 + (size_t)tt * DD1 + dir * HH + u;
            if (BF16OUT) ((__hip_bfloat16*)out0)[oidx] = __float2bfloat16(h);
            else         ((float*)out0)[oidx] = h;
        }
        __syncthreads();
    }
}

// ---------------------------------------------------------------------------
// Layer 1 forward: one row per block, 512 threads. Thread (q = tid>>8,
// g = tid&255) computes half q of gate g's dot product: 64 input-k +
// 32 h-k = 96 weight floats PINNED in registers (~115 VGPR) -> 2 blocks/CU.
// Partials reduced via LDS gs[2][256]; one wave prefetches the next tile.
// ---------------------------------------------------------------------------
template <bool BF16IN>
__launch_bounds__(512, 4)
__global__ void lstm_l1(const void* __restrict__ in0,
                        const float* __restrict__ w_ih, const float* __restrict__ w_hh,
                        const float* __restrict__ b_ih, const float* __restrict__ b_hh,
                        float* __restrict__ h_last) {
    const int tid = threadIdx.x;
    const int row = blockIdx.x;
    const int q   = tid >> 8;   // 0 or 1
    const int g   = tid & 255;

    __shared__ __align__(16) float ins[2][DD1];  // double-buffered input tile
    __shared__ __align__(16) float hs[HH];
    __shared__ __align__(16) float gs[2][GG];
    __shared__ __align__(16) float bs[GG];

    float wih[64];
#pragma unroll
    for (int k = 0; k < 16; ++k) ((float4*)wih)[k] = ((const float4*)(w_ih + g * DD1 + q * 64))[k];
    float whh[32];
#pragma unroll
    for (int k = 0; k < 8; ++k) ((float4*)whh)[k] = ((const float4*)(w_hh + g * HH + q * 32))[k];
    PIN_F(wih, 64);
    PIN_F(whh, 32);

    if (tid < GG) bs[tid] = b_ih[tid] + b_hh[tid];
    if (tid < HH) hs[tid] = 0.0f;

    const bool pfw = (tid >= 256 && tid < 320);  // one wave prefetches
    const int  pj  = tid - 256;

    auto load_in = [&](int t, float2* v) {
        size_t base = ((size_t)row * TT + t) * DD1 + pj * 2;
        if (BF16IN) {
            const __hip_bfloat16* p = (const __hip_bfloat16*)in0 + base;
            v->x = __bfloat162float(p[0]);
            v->y = __bfloat162float(p[1]);
        } else {
            *v = *(const float2*)((const float*)in0 + base);
        }
    };

    if (pfw) {  // stage t = 0
        float2 v;
        load_in(0, &v);
        ((float2*)ins[0])[pj] = v;
    }
    float c = 0.0f;
    __syncthreads();

    for (int t = 0; t < TT; ++t) {
        const int cur = t & 1;
        float2 pf;
        if (pfw && t + 1 < TT) load_in(t + 1, &pf);  // issue early

        // gate phase: uniform LDS broadcasts + pinned register weights
        float a0 = 0.f, a1 = 0.f, a2 = 0.f, a3 = 0.f;
        const float4* in4 = (const float4*)&ins[cur][q * 64];
#pragma unroll
        for (int kk = 0; kk < 16; ++kk) {
            float4 iv = in4[kk];
            a0 += wih[4 * kk + 0] * iv.x;
            a1 += wih[4 * kk + 1] * iv.y;
            a2 += wih[4 * kk + 2] * iv.z;
            a3 += wih[4 * kk + 3] * iv.w;
        }
        const float4* h4 = (const float4*)&hs[q * 32];
#pragma unroll
        for (int kk = 0; kk < 8; ++kk) {
            float4 hv = h4[kk];
            a0 += whh[4 * kk + 0] * hv.x;
            a1 += whh[4 * kk + 1] * hv.y;
            a2 += whh[4 * kk + 2] * hv.z;
            a3 += whh[4 * kk + 3] * hv.w;
        }
        gs[q][g] = (a0 + a1) + (a2 + a3);
        __syncthreads();

        if (tid < HH) {
            const int u = tid;
            float gi = gs[0][u]       + gs[1][u]       + bs[u];
            float gf = gs[0][u + 64]  + gs[1][u + 64]  + bs[u + 64];
            float gc = gs[0][u + 128] + gs[1][u + 128] + bs[u + 128];
            float go = gs[0][u + 192] + gs[1][u + 192] + bs[u + 192];
            c = sigf(gf) * c + sigf(gi) * tanh_fast(gc);
            float h = sigf(go) * tanh_fast(c);
            hs[u] = h;
            if (t == TT - 1) h_last[(size_t)row * HH + u] = h;
        }
        if (pfw && t + 1 < TT) ((float2*)ins[cur ^ 1])[pj] = pf;
        __syncthreads();
    }
}

// ---------------------------------------------------------------------------
// Tail: layer-1 backward is ONE step at t = T-1 from zero state (h0=0 kills
// the w_hh term), then FC. grid = 1024 blocks (one per batch), 256 threads.
// ---------------------------------------------------------------------------
template <bool BF16IN>
__global__ void lstm_tail(const void* __restrict__ in0,
                          const float* __restrict__ h1f,
                          const float* __restrict__ w_ih_r,
                          const float* __restrict__ b_ih_r, const float* __restrict__ b_hh_r,
                          const float* __restrict__ fc_w, const float* __restrict__ fc_b,
                          float* __restrict__ out) {
    const int b   = blockIdx.x;
    const int tid = threadIdx.x;
    __shared__ __align__(16) float insl[DD1];
    __shared__ __align__(16) float hb[HH];
    __shared__ __align__(16) float gsh[GG];

    if (tid < DD1) {
        size_t base = ((size_t)b * TT + (TT - 1)) * DD1 + tid;
        insl[tid] = BF16IN ? __bfloat162float(((const __hip_bfloat16*)in0)[base])
                           : ((const float*)in0)[base];
    }
    __syncthreads();

    float a0 = b_ih_r[tid] + b_hh_r[tid], a1 = 0.f, a2 = 0.f, a3 = 0.f;
    const float4* in4 = (const float4*)insl;
#pragma unroll
    for (int kk = 0; kk < 32; ++kk) {
        float4 iv = in4[kk];
        float4 wv = *(const float4*)&w_ih_r[tid * DD1 + 4 * kk];
        a0 += wv.x * iv.x;
        a1 += wv.y * iv.y;
        a2 += wv.z * iv.z;
        a3 += wv.w * iv.w;
    }
    gsh[tid] = (a0 + a1) + (a2 + a3);
    __syncthreads();

    if (tid < HH) {
        float gi = gsh[tid], gc = gsh[tid + 128], go = gsh[tid + 192];
        float cc = sigf(gi) * tanh_fast(gc);  // c_prev = 0
        hb[tid] = sigf(go) * tanh_fast(cc);
    }
    __syncthreads();

    if (tid < 64) {
        float p = fc_w[tid] * h1f[(size_t)b * HH + tid] + fc_w[HH + tid] * hb[tid];
#pragma unroll
        for (int off = 32; off; off >>= 1) p += __shfl_xor(p, off);
        if (tid == 0) out[b] = p + fc_b[0];
    }
}

// ---------------------------------------------------------------------------
extern "C" void kernel_launch(void* const* d_in, const int* in_sizes, int n_in,
                              void* d_out, int out_size, void* d_ws, size_t ws_size,
                              hipStream_t stream) {
    const float* x = (const float*)d_in[0];
    // l0 fwd: 1..4, l0 rev: 5..8, l1 fwd: 9..12, l1 rev: 13..16, fc: 17,18
    const size_t out0_f32_bytes = (size_t)NB * TT * DD1 * sizeof(float);  // 134 MB
    const size_t hlast_bytes    = (size_t)NB * HH * sizeof(float);

    const bool bf16 = (ws_size < out0_f32_bytes + hlast_bytes);
    char* ws = (char*)d_ws;
    void* out0 = (void*)ws;
    const size_t out0_bytes = bf16 ? out0_f32_bytes / 2 : out0_f32_bytes;
    float* h1f = (float*)(ws + out0_bytes);

    if (!bf16) {
        lstm_l0<false><<<2048, 256, 0, stream>>>(
            x, (const float*)d_in[1], (const float*)d_in[2], (const float*)d_in[3], (const float*)d_in[4],
            (const float*)d_in[5], (const float*)d_in[6], (const float*)d_in[7], (const float*)d_in[8], out0);
        lstm_l1<false><<<1024, 512, 0, stream>>>(
            out0, (const float*)d_in[9], (const float*)d_in[10], (const float*)d_in[11], (const float*)d_in[12], h1f);
        lstm_tail<false><<<1024, 256, 0, stream>>>(
            out0, h1f, (const float*)d_in[13], (const float*)d_in[15], (const float*)d_in[16],
            (const float*)d_in[17], (const float*)d_in[18], (float*)d_out);
    } else {
        lstm_l0<true><<<2048, 256, 0, stream>>>(
            x, (const float*)d_in[1], (const float*)d_in[2], (const float*)d_in[3], (const float*)d_in[4],
            (const float*)d_in[5], (const float*)d_in[6], (const float*)d_in[7], (const float*)d_in[8], out0);
        lstm_l1<true><<<1024, 512, 0, stream>>>(
            out0, (const float*)d_in[9], (const float*)d_in[10], (const float*)d_in[11], (const float*)d_in[12], h1f);
        lstm_tail<true><<<1024, 256, 0, stream>>>(
            out0, h1f, (const float*)d_in[13], (const float*)d_in[15], (const float*)d_in[16],
            (const float*)d_in[17], (const float*)d_in[18], (float*)d_out);
    }
}

// Round 4
// 858.259 us; speedup vs baseline: 6.2616x; 6.2616x over previous
//
#include <hip/hip_runtime.h>
#include <hip/hip_bf16.h>

#define HH 64      // hidden
#define TT 256     // seq len
#define NB 1024    // batch
#define DD0 5      // layer-0 input dim
#define DD1 128    // layer-1 input dim (2*H)

typedef __attribute__((ext_vector_type(8))) short bf16x8;  // 8 bf16 = 4 VGPR
typedef __attribute__((ext_vector_type(4))) float f32x4;   // MFMA C/D frag

#define MFMA16(a, b, c) __builtin_amdgcn_mfma_f32_16x16x32_bf16((a), (b), (c), 0, 0, 0)

__device__ __forceinline__ float sigf(float x) { return 1.0f / (1.0f + __expf(-x)); }
__device__ __forceinline__ float tanh_fast(float x) { return 2.0f / (1.0f + __expf(-2.0f * x)) - 1.0f; }

__device__ __forceinline__ float bf2f(short s) {
    unsigned int u = ((unsigned int)(unsigned short)s) << 16;
    return __builtin_bit_cast(float, u);
}
__device__ __forceinline__ short f2bf_rne(float x) {
    unsigned int u = __builtin_bit_cast(unsigned int, x);
    u += 0x7fffu + ((u >> 16) & 1u);  // round-to-nearest-even
    return (short)(u >> 16);
}

// ---------------------------------------------------------------------------
// Layer 0, MFMA recurrence. 256 blocks = 2 dirs x 128 row-groups of 8 rows.
// 256 threads = 4 waves; wave w owns n-tile quad {w, w+4, w+8, w+12} so each
// lane gets i,f,g,o of unit u = 16w + (lane&15) in its own accumulators
// (C/D: col = lane&15, row = (lane>>4)*4 + reg). h = split-bf16 (hi+lo) via
// 3-combo MFMA; x-part (D=5) exact fp32 in the update. One barrier/step
// (double-buffered hs). Output: out0[b][t][0:128]=h_hi (fwd|bwd),
// [128:256]=h_lo — the exact hi/lo pair layer 1 consumes as A-fragments.
// ---------------------------------------------------------------------------
__launch_bounds__(256, 2)
__global__ void lstm_l0(const float* __restrict__ x,
                        const float* __restrict__ w_ih_f, const float* __restrict__ w_hh_f,
                        const float* __restrict__ b_ih_f, const float* __restrict__ b_hh_f,
                        const float* __restrict__ w_ih_r, const float* __restrict__ w_hh_r,
                        const float* __restrict__ b_ih_r, const float* __restrict__ b_hh_r,
                        short* __restrict__ out0) {
    const int tid  = threadIdx.x;
    const int w    = tid >> 6;
    const int l    = tid & 63;
    const int col  = l & 15;   // A-row / C-col index
    const int rg   = l >> 4;
    const int dir  = blockIdx.x >> 7;
    const int row0 = (blockIdx.x & 127) * 8;
    const int u    = w * 16 + col;  // hidden unit this lane updates

    const float* w_ih = dir ? w_ih_r : w_ih_f;
    const float* w_hh = dir ? w_hh_r : w_hh_f;
    const float* b_ih = dir ? b_ih_r : b_ih_f;
    const float* b_hh = dir ? b_hh_r : b_hh_f;

    __shared__ __align__(16) float xs[8][TT * DD0];   // 40 KB: block's x, all t
    __shared__ __align__(16) short hs[2][16][136];    // [hi 0..63 | lo 64..127 | pad]

    {   // stage x (8 rows x 1280 contiguous floats)
        const float4* src = (const float4*)(x + (size_t)row0 * TT * DD0);
        float4* dst = (float4*)&xs[0][0];
        for (int i = tid; i < 8 * TT * DD0 / 4; i += 256) dst[i] = src[i];
    }
    for (int i = tid; i < 2 * 16 * 136; i += 256) ((short*)hs)[i] = 0;

    // w_hh B-fragments (split-bf16), 4 n-tiles x 2 k-steps, in registers
    bf16x8 whh_hi[4][2], whh_lo[4][2];
#pragma unroll
    for (int q = 0; q < 4; ++q) {
        const int gate = (w + 4 * q) * 16 + col;
#pragma unroll
        for (int ks = 0; ks < 2; ++ks) {
            const float* src = w_hh + gate * HH + ks * 32 + 8 * rg;
#pragma unroll
            for (int e = 0; e < 8; ++e) {
                float v = src[e];
                short h16 = f2bf_rne(v);
                whh_hi[q][ks][e] = h16;
                whh_lo[q][ks][e] = f2bf_rne(v - bf2f(h16));
            }
        }
    }
    // x weights (exact fp32) + bias for this lane's 4 gates (i,f,g,o of unit u)
    float wxi[4][DD0], bb[4];
#pragma unroll
    for (int gi = 0; gi < 4; ++gi) {
        const int gate = u + 64 * gi;
#pragma unroll
        for (int d = 0; d < DD0; ++d) wxi[gi][d] = w_ih[gate * DD0 + d];
        bb[gi] = b_ih[gate] + b_hh[gate];
    }

    f32x4 c = {0.f, 0.f, 0.f, 0.f};
    __syncthreads();

    for (int t = 0; t < TT; ++t) {
        const int tt  = dir ? (TT - 1 - t) : t;
        const int cur = t & 1;
        const short* hrow = &hs[cur][col][0];
        bf16x8 ah0 = *(const bf16x8*)&hrow[ 0 + 8 * rg];  // hi k 0..31
        bf16x8 ah1 = *(const bf16x8*)&hrow[32 + 8 * rg];  // hi k 32..63
        bf16x8 ah2 = *(const bf16x8*)&hrow[64 + 8 * rg];  // lo k 0..31
        bf16x8 ah3 = *(const bf16x8*)&hrow[96 + 8 * rg];  // lo k 32..63
        f32x4 acc[4];
#pragma unroll
        for (int q = 0; q < 4; ++q) {
            f32x4 a = {0.f, 0.f, 0.f, 0.f};
            a = MFMA16(ah0, whh_hi[q][0], a);
            a = MFMA16(ah1, whh_hi[q][1], a);
            a = MFMA16(ah2, whh_hi[q][0], a);   // h_lo * w_hi
            a = MFMA16(ah3, whh_hi[q][1], a);
            a = MFMA16(ah0, whh_lo[q][0], a);   // h_hi * w_lo
            a = MFMA16(ah1, whh_lo[q][1], a);
            acc[q] = a;
        }
        if (rg < 2) {  // rows rg*4 .. rg*4+3 valid (block has 8 rows)
            const int nxt = cur ^ 1;
#pragma unroll
            for (int r = 0; r < 4; ++r) {
                const int row = rg * 4 + r;
                const float* xr = &xs[row][tt * DD0];
                const float xv0 = xr[0], xv1 = xr[1], xv2 = xr[2], xv3 = xr[3], xv4 = xr[4];
                float g4[4];
#pragma unroll
                for (int gi = 0; gi < 4; ++gi)
                    g4[gi] = acc[gi][r] + bb[gi]
                           + wxi[gi][0] * xv0 + wxi[gi][1] * xv1 + wxi[gi][2] * xv2
                           + wxi[gi][3] * xv3 + wxi[gi][4] * xv4;
                const float cn = sigf(g4[1]) * c[r] + sigf(g4[0]) * tanh_fast(g4[2]);
                const float hn = sigf(g4[3]) * tanh_fast(cn);
                c[r] = cn;
                const short hi16 = f2bf_rne(hn);
                const short lo16 = f2bf_rne(hn - bf2f(hi16));
                hs[nxt][row][u]      = hi16;
                hs[nxt][row][64 + u] = lo16;
                const size_t ob = ((size_t)(row0 + row) * TT + tt) * 256;
                out0[ob + dir * 64 + u]       = hi16;
                out0[ob + 128 + dir * 64 + u] = lo16;
            }
        }
        __syncthreads();  // one barrier/step: hs double-buffered
    }
}

// ---------------------------------------------------------------------------
// Layer 1 forward, fused MFMA recurrence: gates = [x_t | h] @ [W_ih | W_hh]^T.
// 128 blocks x 8 rows, 256 threads (4 waves, same quad layout). W_ih frags
// (hi+lo) staged in LDS (128 KB); W_hh frags in regs. x A-frags prefetched
// from global one step ahead. Only final h stored.
// ---------------------------------------------------------------------------
__launch_bounds__(256, 1)
__global__ void lstm_l1(const short* __restrict__ in0,
                        const float* __restrict__ w_ih, const float* __restrict__ w_hh,
                        const float* __restrict__ b_ih, const float* __restrict__ b_hh,
                        float* __restrict__ h_last) {
    const int tid  = threadIdx.x;
    const int w    = tid >> 6;
    const int l    = tid & 63;
    const int col  = l & 15;
    const int rg   = l >> 4;
    const int row0 = blockIdx.x * 8;
    const int u    = w * 16 + col;

    __shared__ __align__(16) short sh_wf[128][64 * 8];  // [nt*8 + sel][lane*8], 128 KB
    __shared__ __align__(16) short hs[2][16][136];

    for (int i = tid; i < 2 * 16 * 136; i += 256) ((short*)hs)[i] = 0;

    // stage W_ih fragments: 64 hi-frag units, each wave does 16 (writes hi+lo)
    for (int it = 0; it < 16; ++it) {
        const int fih = w * 16 + it;         // = nt*4 + ks
        const int nt = fih >> 2, ks = fih & 3;
        const float* src = w_ih + (nt * 16 + col) * DD1 + ks * 32 + 8 * rg;
        bf16x8 hi, lo;
#pragma unroll
        for (int e = 0; e < 8; ++e) {
            float v = src[e];
            short h16 = f2bf_rne(v);
            hi[e] = h16;
            lo[e] = f2bf_rne(v - bf2f(h16));
        }
        *(bf16x8*)&sh_wf[nt * 8 + ks][l * 8]     = hi;
        *(bf16x8*)&sh_wf[nt * 8 + 4 + ks][l * 8] = lo;
    }

    bf16x8 whh_hi[4][2], whh_lo[4][2];
#pragma unroll
    for (int q = 0; q < 4; ++q) {
        const int gate = (w + 4 * q) * 16 + col;
#pragma unroll
        for (int ks = 0; ks < 2; ++ks) {
            const float* src = w_hh + gate * HH + ks * 32 + 8 * rg;
#pragma unroll
            for (int e = 0; e < 8; ++e) {
                float v = src[e];
                short h16 = f2bf_rne(v);
                whh_hi[q][ks][e] = h16;
                whh_lo[q][ks][e] = f2bf_rne(v - bf2f(h16));
            }
        }
    }
    float bb[4];
#pragma unroll
    for (int gi = 0; gi < 4; ++gi) bb[gi] = b_ih[u + 64 * gi] + b_hh[u + 64 * gi];

    // x A-fragment source (A rows 8..15 clamped — their C rows are never read)
    const int arow = row0 + (col < 8 ? col : 7);
    const short* xsrc = in0 + (size_t)arow * TT * 256 + 8 * rg;

    f32x4 c = {0.f, 0.f, 0.f, 0.f};
    bf16x8 xA[8], xB[8];

    auto loadx = [&](int t, bf16x8 (&xr)[8]) {
        const short* p = xsrc + (size_t)t * 256;
#pragma unroll
        for (int ks = 0; ks < 4; ++ks) {
            xr[ks]     = *(const bf16x8*)&p[ks * 32];        // x_hi, k-step ks
            xr[4 + ks] = *(const bf16x8*)&p[128 + ks * 32];  // x_lo
        }
    };

    auto step = [&](int t, const bf16x8 (&xr)[8]) {
        const int cur = t & 1;
        const short* hrow = &hs[cur][col][0];
        bf16x8 ah0 = *(const bf16x8*)&hrow[ 0 + 8 * rg];
        bf16x8 ah1 = *(const bf16x8*)&hrow[32 + 8 * rg];
        bf16x8 ah2 = *(const bf16x8*)&hrow[64 + 8 * rg];
        bf16x8 ah3 = *(const bf16x8*)&hrow[96 + 8 * rg];
        f32x4 acc[4];
#pragma unroll
        for (int q = 0; q < 4; ++q) {
            const int nt = w + 4 * q;
            f32x4 a = {0.f, 0.f, 0.f, 0.f};
            a = MFMA16(ah0, whh_hi[q][0], a);
            a = MFMA16(ah1, whh_hi[q][1], a);
            a = MFMA16(ah2, whh_hi[q][0], a);
            a = MFMA16(ah3, whh_hi[q][1], a);
            a = MFMA16(ah0, whh_lo[q][0], a);
            a = MFMA16(ah1, whh_lo[q][1], a);
#pragma unroll
            for (int ks = 0; ks < 4; ++ks) {
                bf16x8 wh = *(const bf16x8*)&sh_wf[nt * 8 + ks][l * 8];
                bf16x8 wl = *(const bf16x8*)&sh_wf[nt * 8 + 4 + ks][l * 8];
                a = MFMA16(xr[ks], wh, a);       // x_hi * w_hi
                a = MFMA16(xr[4 + ks], wh, a);   // x_lo * w_hi
                a = MFMA16(xr[ks], wl, a);       // x_hi * w_lo
            }
            acc[q] = a;
        }
        if (rg < 2) {
            const int nxt = cur ^ 1;
#pragma unroll
            for (int r = 0; r < 4; ++r) {
                const int row = rg * 4 + r;
                const float gi_ = acc[0][r] + bb[0];
                const float gf_ = acc[1][r] + bb[1];
                const float gg_ = acc[2][r] + bb[2];
                const float go_ = acc[3][r] + bb[3];
                const float cn = sigf(gf_) * c[r] + sigf(gi_) * tanh_fast(gg_);
                const float hn = sigf(go_) * tanh_fast(cn);
                c[r] = cn;
                const short hi16 = f2bf_rne(hn);
                hs[nxt][row][u]      = hi16;
                hs[nxt][row][64 + u] = f2bf_rne(hn - bf2f(hi16));
                if (t == TT - 1) h_last[(size_t)(row0 + row) * HH + u] = hn;
            }
        }
        __syncthreads();
    };

    loadx(0, xA);
    __syncthreads();
    for (int t = 0; t < TT; t += 2) {
        loadx(t + 1, xB);            // in flight under step t
        step(t, xA);
        if (t + 2 < TT) loadx(t + 2, xA);
        step(t + 1, xB);
    }
}

// ---------------------------------------------------------------------------
// Tail: layer-1 backward is ONE step at t=T-1 from zero state (h0=0 kills the
// w_hh term), then FC. in0 reconstructed from hi+lo. 1024 blocks, 256 threads.
// ---------------------------------------------------------------------------
__global__ void lstm_tail(const short* __restrict__ in0,
                          const float* __restrict__ h1f,
                          const float* __restrict__ w_ih_r,
                          const float* __restrict__ b_ih_r, const float* __restrict__ b_hh_r,
                          const float* __restrict__ fc_w, const float* __restrict__ fc_b,
                          float* __restrict__ out) {
    const int b   = blockIdx.x;
    const int tid = threadIdx.x;
    __shared__ __align__(16) float insl[DD1];
    __shared__ __align__(16) float hb[HH];
    __shared__ __align__(16) float gsh[256];

    if (tid < DD1) {
        const size_t base = ((size_t)b * TT + (TT - 1)) * 256;
        insl[tid] = bf2f(in0[base + tid]) + bf2f(in0[base + 128 + tid]);
    }
    __syncthreads();

    float a0 = b_ih_r[tid] + b_hh_r[tid], a1 = 0.f, a2 = 0.f, a3 = 0.f;
    const float4* in4 = (const float4*)insl;
#pragma unroll
    for (int kk = 0; kk < 32; ++kk) {
        float4 iv = in4[kk];
        float4 wv = *(const float4*)&w_ih_r[tid * DD1 + 4 * kk];
        a0 += wv.x * iv.x;
        a1 += wv.y * iv.y;
        a2 += wv.z * iv.z;
        a3 += wv.w * iv.w;
    }
    gsh[tid] = (a0 + a1) + (a2 + a3);
    __syncthreads();

    if (tid < HH) {
        const float gi = gsh[tid], gc = gsh[tid + 128], go = gsh[tid + 192];
        const float cc = sigf(gi) * tanh_fast(gc);  // c_prev = 0
        hb[tid] = sigf(go) * tanh_fast(cc);
    }
    __syncthreads();

    if (tid < 64) {
        float p = fc_w[tid] * h1f[(size_t)b * HH + tid] + fc_w[HH + tid] * hb[tid];
#pragma unroll
        for (int off = 32; off; off >>= 1) p += __shfl_xor(p, off);
        if (tid == 0) out[b] = p + fc_b[0];
    }
}

// ---------------------------------------------------------------------------
extern "C" void kernel_launch(void* const* d_in, const int* in_sizes, int n_in,
                              void* d_out, int out_size, void* d_ws, size_t ws_size,
                              hipStream_t stream) {
    const float* x = (const float*)d_in[0];
    // l0 fwd: 1..4, l0 rev: 5..8, l1 fwd: 9..12, l1 rev: 13..16, fc: 17,18
    char* ws = (char*)d_ws;
    short* out0 = (short*)ws;                                  // [1024][256][256] bf16, 134.2 MB
    float* h1f  = (float*)(ws + (size_t)NB * TT * 256 * 2);    // [1024][64] f32

    lstm_l0<<<256, 256, 0, stream>>>(
        x, (const float*)d_in[1], (const float*)d_in[2], (const float*)d_in[3], (const float*)d_in[4],
        (const float*)d_in[5], (const float*)d_in[6], (const float*)d_in[7], (const float*)d_in[8], out0);
    lstm_l1<<<128, 256, 0, stream>>>(
        out0, (const float*)d_in[9], (const float*)d_in[10], (const float*)d_in[11], (const float*)d_in[12], h1f);
    lstm_tail<<<1024, 256, 0, stream>>>(
        out0, h1f, (const float*)d_in[13], (const float*)d_in[15], (const float*)d_in[16],
        (const float*)d_in[17], (const float*)d_in[18], (float*)d_out);
}